// Round 1
// baseline (124.355 us; speedup 1.0000x reference)
//
#include <hip/hip_runtime.h>
#include <cstdint>
#include <cstddef>

#define BN 32
#define PN 1000
#define GN 24
#define NPTSN 72
#define DNN 78
#define CHN 8          // pred chunks in K1
#define PPCN 125       // preds per chunk (8*125 = 1000)
#define EPSF 1e-8f
#define INF __builtin_inff()

// ---- workspace layout (units of 4 bytes) ----
#define OFF_DIST  0
#define OFF_LIOU  (OFF_DIST + BN*GN*PN)          // 768000
#define OFF_PX    (OFF_LIOU + BN*GN*PN)
#define OFF_PY    (OFF_PX + BN*PN)
#define OFF_PTH   (OFF_PY + BN*PN)
#define OFF_CLS   (OFF_PTH + BN*PN)
#define OFF_PART  (OFF_CLS + BN*PN)              // BN*CHN*3 floats
#define OFF_CAND  (OFF_PART + BN*CHN*3)          // BN*GN*4 ints
#define OFF_KS    (OFF_CAND + BN*GN*4)           // BN*GN ints
// total ~1.67M elements = ~6.7 MB

// ---------- helpers ----------
__device__ __forceinline__ unsigned ordf(float f) {
  unsigned u = __float_as_uint(f);
  return (u & 0x80000000u) ? ~u : (u | 0x80000000u);
}
__device__ __forceinline__ float unordf(unsigned u) {
  return __uint_as_float((u & 0x80000000u) ? (u ^ 0x80000000u) : ~u);
}
__device__ __forceinline__ unsigned long long shfl_down_u64(unsigned long long v, int off) {
  unsigned lo = (unsigned)(v & 0xffffffffull);
  unsigned hi = (unsigned)(v >> 32);
  lo = __shfl_down(lo, off);
  hi = __shfl_down(hi, off);
  return (((unsigned long long)hi) << 32) | (unsigned long long)lo;
}

// masks may arrive as int32 (expected), uint8 (raw bool), or float32.
// mask[b][g] = g < num_gt[b], num_gt>=1 -> mask[*][0] always true, which
// makes the layouts distinguishable. Must be called by ALL threads of block.
__device__ int detect_mask_layout(const void* masks, int* sflag) {
  const unsigned* mw = (const unsigned*)masks;
  if (mw[0] == 0x3f800000u) return 2;   // float32 1.0f (uniform decision)
  if (threadIdx.x == 0) *sflag = 0;
  __syncthreads();
  const unsigned char* mb = (const unsigned char*)masks;
  int local = 0;
  for (int i = threadIdx.x; i < BN * GN; i += blockDim.x)
    if ((i & 3) != 0 && mb[i] != 0) local = 1;   // int32 0/1 never has these bytes set
  if (local) atomicOr(sflag, 1);
  __syncthreads();
  return (*sflag) ? 1 : 0;
}
__device__ __forceinline__ int mask_val(const void* masks, int layout, int idx) {
  if (layout == 2) return ((const float*)masks)[idx] != 0.0f;
  if (layout == 1) return ((const unsigned char*)masks)[idx] != 0;
  return ((const int*)masks)[idx] != 0;
}

// ---------- K1: per (b, pred-chunk): S-sums -> dist, liou; partial maxima ----------
__global__ __launch_bounds__(512) void clr_k1(
    const float* __restrict__ preds, const float* __restrict__ targets,
    const void* __restrict__ masks, const int* __restrict__ imw,
    const int* __restrict__ imh, float* __restrict__ ws)
{
  const int b = blockIdx.y;
  const int c = blockIdx.x;
  const int tid = threadIdx.x;
  const int pl = tid & 127;        // pred lane within chunk
  const int gq = tid >> 7;         // 0..3, each handles 6 targets
  const int p = c * PPCN + pl;
  const bool active = (pl < PPCN);
  const float wf = (float)imw[0];
  const float hm1 = (float)imh[0] - 1.0f;
  const float wm1 = wf - 1.0f;

  __shared__ __align__(16) float tp[GN][NPTSN];
  __shared__ float tgx[GN], tgy[GN], tgth[GN], tvl[GN];
  __shared__ int gm[GN];
  __shared__ float red[8][3];
  __shared__ int sflag;

  const int mlay = detect_mask_layout(masks, &sflag);

  for (int idx = tid; idx < GN * NPTSN; idx += 512) {
    int g = idx / NPTSN;
    int j = idx - g * NPTSN;
    tp[g][j] = targets[((size_t)(b * GN + g)) * DNN + 6 + j] * wm1;
  }
  if (tid < GN) {
    const float* tr = targets + ((size_t)(b * GN + tid)) * DNN;
    tgx[tid] = tr[2] * hm1;
    tgy[tid] = tr[3] * wm1;
    tgth[tid] = tr[4] * 180.0f;
    gm[tid] = mask_val(masks, mlay, b * GN + tid);
  }
  __syncthreads();
  if (tid < GN) {
    float cnt = 0.0f;
    for (int j = 0; j < NPTSN; j++) {
      float t = tp[tid][j];
      if (t >= 0.0f && t < wf) cnt += 1.0f;
    }
    tvl[tid] = fmaxf(cnt, 1.0f);
  }
  __syncthreads();

  float pp[NPTSN];
  float ppx = 0.f, ppy = 0.f, ppth = 0.f;
  if (active) {
    const float* row = preds + ((size_t)(b * PN + p)) * DNN;
    const float2* r2 = (const float2*)(row + 6);   // always 8B-aligned
    #pragma unroll
    for (int j = 0; j < NPTSN / 2; j++) {
      float2 v = r2[j];
      pp[2 * j]     = v.x * wm1;
      pp[2 * j + 1] = v.y * wm1;
    }
    ppx  = row[2] * hm1;
    ppy  = row[3] * wm1;
    ppth = row[4] * 180.0f;
    if (gq == 0) {
      float x0 = row[0], x1 = row[1];
      float m = fmaxf(x0, x1);
      float e0 = expf(x0 - m), e1 = expf(x1 - m);
      float p1 = fmaxf(e1 / (e0 + e1), EPSF);
      ws[OFF_PX  + b * PN + p] = ppx;
      ws[OFF_PY  + b * PN + p] = ppy;
      ws[OFF_PTH + b * PN + p] = ppth;
      ws[OFF_CLS + b * PN + p] = -logf(p1);
    }
  } else {
    #pragma unroll
    for (int j = 0; j < NPTSN; j++) pp[j] = 0.0f;
  }

  float mxd = -INF, mxs = -INF, mxt = -INF;
  for (int i = 0; i < 6; i++) {
    const int g = gq * 6 + i;
    float S = 0.0f;
    const float4* t4p = (const float4*)(&tp[g][0]);
    #pragma unroll
    for (int jj = 0; jj < NPTSN / 4; jj++) {
      float4 t = t4p[jj];
      float a0 = fabsf(pp[4 * jj + 0] - t.x);
      float a1 = fabsf(pp[4 * jj + 1] - t.y);
      float a2 = fabsf(pp[4 * jj + 2] - t.z);
      float a3 = fabsf(pp[4 * jj + 3] - t.w);
      S += (t.x >= 0.0f && t.x < wf) ? a0 : 0.0f;
      S += (t.y >= 0.0f && t.y < wf) ? a1 : 0.0f;
      S += (t.z >= 0.0f && t.z < wf) ? a2 : 0.0f;
      S += (t.w >= 0.0f && t.w < wf) ? a3 : 0.0f;
    }
    if (active) {
      float VL = tvl[g];
      float dist = S / VL;
      float liou = (30.0f * VL - S) / (30.0f * VL + S + 1e-9f);
      size_t o = ((size_t)(b * GN + g)) * PN + p;
      ws[OFF_DIST + o] = dist;
      ws[OFF_LIOU + o] = liou;
      float dx = ppx - tgx[g], dy = ppy - tgy[g];
      float sd = sqrtf(dx * dx + dy * dy);
      float td = fabsf(ppth - tgth[g]);
      if (gm[g]) {
        mxd = fmaxf(mxd, dist);
        mxs = fmaxf(mxs, sd);
        mxt = fmaxf(mxt, td);
      }
    }
  }

  #pragma unroll
  for (int off = 32; off > 0; off >>= 1) {
    mxd = fmaxf(mxd, __shfl_down(mxd, off));
    mxs = fmaxf(mxs, __shfl_down(mxs, off));
    mxt = fmaxf(mxt, __shfl_down(mxt, off));
  }
  const int wv = tid >> 6;
  if ((tid & 63) == 0) { red[wv][0] = mxd; red[wv][1] = mxs; red[wv][2] = mxt; }
  __syncthreads();
  if (tid == 0) {
    float a = red[0][0], s = red[0][1], t = red[0][2];
    for (int i = 1; i < 8; i++) {
      a = fmaxf(a, red[i][0]);
      s = fmaxf(s, red[i][1]);
      t = fmaxf(t, red[i][2]);
    }
    ws[OFF_PART + (b * CHN + c) * 3 + 0] = a;
    ws[OFF_PART + (b * CHN + c) * 3 + 1] = s;
    ws[OFF_PART + (b * CHN + c) * 3 + 2] = t;
  }
}

// ---------- K2: per (b,g): cost, top-4 min cost (stable), top-4 max liou -> ks ----------
__global__ __launch_bounds__(256) void clr_k2(
    const float* __restrict__ targets, const int* __restrict__ imw,
    const int* __restrict__ imh, float* __restrict__ ws)
{
  const int g = blockIdx.x;
  const int b = blockIdx.y;
  const int tid = threadIdx.x;
  const float wf = (float)imw[0];
  const float hm1 = (float)imh[0] - 1.0f;
  const float wm1 = wf - 1.0f;

  float Md = -INF, Ms = -INF, Mt = -INF;
  for (int c = 0; c < CHN; c++) {
    Md = fmaxf(Md, ws[OFF_PART + (b * CHN + c) * 3 + 0]);
    Ms = fmaxf(Ms, ws[OFF_PART + (b * CHN + c) * 3 + 1]);
    Mt = fmaxf(Mt, ws[OFF_PART + (b * CHN + c) * 3 + 2]);
  }
  const float* tr = targets + ((size_t)(b * GN + g)) * DNN;
  const float tx = tr[2] * hm1, ty = tr[3] * wm1, tth = tr[4] * 180.0f;

  unsigned long long ck[4], lk[4];
  #pragma unroll
  for (int i = 0; i < 4; i++) { ck[i] = ~0ull; lk[i] = ~0ull; }
  const size_t base = ((size_t)(b * GN + g)) * PN;
  #pragma unroll
  for (int i = 0; i < 4; i++) {
    int p = tid + i * 256;
    if (p < PN) {
      float dist = ws[OFF_DIST + base + p];
      float liou = ws[OFF_LIOU + base + p];
      float px  = ws[OFF_PX  + b * PN + p];
      float py  = ws[OFF_PY  + b * PN + p];
      float pth = ws[OFF_PTH + b * PN + p];
      float cls = ws[OFF_CLS + b * PN + p];
      float dsc = (1.0f - dist / (Md + EPSF)) + 0.01f;
      float dx = px - tx, dy = py - ty;
      float sd = sqrtf(dx * dx + dy * dy);
      float xsc = (1.0f - sd / (Ms + EPSF)) + 0.01f;
      float tsc = (1.0f - fabsf(pth - tth) / (Mt + EPSF)) + 0.01f;
      float r = (dsc * xsc) * tsc;
      float cost = -(r * r) * 3.0f + cls;
      ck[i] = (((unsigned long long)ordf(cost)) << 32) | (unsigned)p;
      lk[i] = (((unsigned long long)(~ordf(liou))) << 32) | (unsigned)p;
    }
  }

  __shared__ unsigned long long wred[4];
  __shared__ unsigned long long winner;
  int cand[4];
  float lval[4];

  // 4 passes: smallest cost, ties -> smaller index (stable argsort semantics)
  for (int pass = 0; pass < 4; pass++) {
    unsigned long long m = ck[0];
    #pragma unroll
    for (int i = 1; i < 4; i++) m = (ck[i] < m) ? ck[i] : m;
    #pragma unroll
    for (int off = 32; off > 0; off >>= 1) {
      unsigned long long o = shfl_down_u64(m, off);
      m = (o < m) ? o : m;
    }
    if ((tid & 63) == 0) wred[tid >> 6] = m;
    __syncthreads();
    if (tid == 0) {
      unsigned long long mm = wred[0];
      for (int i = 1; i < 4; i++) mm = (wred[i] < mm) ? wred[i] : mm;
      winner = mm;
    }
    __syncthreads();
    unsigned long long wn = winner;
    __syncthreads();
    #pragma unroll
    for (int i = 0; i < 4; i++) if (ck[i] == wn) ck[i] = ~0ull;
    cand[pass] = (int)(unsigned)(wn & 0xffffffffull);
  }
  // 4 passes: largest liou (descending), for dynamic_ks
  for (int pass = 0; pass < 4; pass++) {
    unsigned long long m = lk[0];
    #pragma unroll
    for (int i = 1; i < 4; i++) m = (lk[i] < m) ? lk[i] : m;
    #pragma unroll
    for (int off = 32; off > 0; off >>= 1) {
      unsigned long long o = shfl_down_u64(m, off);
      m = (o < m) ? o : m;
    }
    if ((tid & 63) == 0) wred[tid >> 6] = m;
    __syncthreads();
    if (tid == 0) {
      unsigned long long mm = wred[0];
      for (int i = 1; i < 4; i++) mm = (wred[i] < mm) ? wred[i] : mm;
      winner = mm;
    }
    __syncthreads();
    unsigned long long wn = winner;
    __syncthreads();
    #pragma unroll
    for (int i = 0; i < 4; i++) if (lk[i] == wn) lk[i] = ~0ull;
    lval[pass] = unordf(~(unsigned)(wn >> 32));
  }

  if (tid == 0) {
    float s = ((lval[0] + lval[1]) + lval[2]) + lval[3];   // descending-order sum like topk.sum(1)
    int k = (int)s;                 // trunc toward zero == astype(int32)
    if (k < 1) k = 1;
    if (k > 4) k = 4;
    int* wsi = (int*)ws;
    wsi[OFF_KS + b * GN + g] = k;
    #pragma unroll
    for (int j = 0; j < 4; j++) wsi[OFF_CAND + (b * GN + g) * 4 + j] = cand[j];
  }
}

// ---------- K3: per batch: counts, resolve multi-match, write outputs ----------
__global__ __launch_bounds__(256) void clr_k3(
    const float* __restrict__ targets, const void* __restrict__ masks,
    const int* __restrict__ imw, const int* __restrict__ imh,
    const float* __restrict__ ws, int* __restrict__ out)
{
  const int b = blockIdx.x;
  const int tid = threadIdx.x;
  const float hm1 = (float)imh[0] - 1.0f;
  const float wm1 = (float)imw[0] - 1.0f;

  __shared__ int counts[PN];
  __shared__ int ksL[GN];
  __shared__ int candL[GN][4];
  __shared__ int gmL[GN];
  __shared__ float tgx[GN], tgy[GN], tgth[GN];
  __shared__ int sflag;

  const int mlay = detect_mask_layout(masks, &sflag);

  for (int i = tid; i < PN; i += 256) counts[i] = 0;
  if (tid < GN) {
    const int* wsi = (const int*)ws;
    ksL[tid] = wsi[OFF_KS + b * GN + tid];
    for (int j = 0; j < 4; j++) candL[tid][j] = wsi[OFF_CAND + (b * GN + tid) * 4 + j];
    gmL[tid] = mask_val(masks, mlay, b * GN + tid);
    const float* tr = targets + ((size_t)(b * GN + tid)) * DNN;
    tgx[tid]  = tr[2] * hm1;
    tgy[tid]  = tr[3] * wm1;
    tgth[tid] = tr[4] * 180.0f;
  }
  __syncthreads();
  if (tid < GN && gmL[tid]) {
    int k = ksL[tid];
    for (int j = 0; j < k; j++) atomicAdd(&counts[candL[tid][j]], 1);
  }
  __syncthreads();

  float Md = -INF, Ms = -INF, Mt = -INF;
  for (int c = 0; c < CHN; c++) {
    Md = fmaxf(Md, ws[OFF_PART + (b * CHN + c) * 3 + 0]);
    Ms = fmaxf(Ms, ws[OFF_PART + (b * CHN + c) * 3 + 1]);
    Mt = fmaxf(Mt, ws[OFF_PART + (b * CHN + c) * 3 + 2]);
  }

  for (int p = tid; p < PN; p += 256) {
    int cnt = counts[p];
    int assigned = 0, matched = -1;
    if (cnt == 1) {
      assigned = 1;
      for (int g = 0; g < GN && matched < 0; g++) {
        if (!gmL[g]) continue;
        int k = ksL[g];
        for (int j = 0; j < k; j++) {
          if (candL[g][j] == p) { matched = g; break; }
        }
      }
    } else if (cnt > 1) {
      assigned = 1;
      float px  = ws[OFF_PX  + b * PN + p];
      float py  = ws[OFF_PY  + b * PN + p];
      float pth = ws[OFF_PTH + b * PN + p];
      float cls = ws[OFF_CLS + b * PN + p];
      float bc = INF; int bg = 0;
      for (int g = 0; g < GN; g++) {
        if (!gmL[g]) continue;
        float dist = ws[OFF_DIST + ((size_t)(b * GN + g)) * PN + p];
        float dsc = (1.0f - dist / (Md + EPSF)) + 0.01f;
        float dx = px - tgx[g], dy = py - tgy[g];
        float sd = sqrtf(dx * dx + dy * dy);
        float xsc = (1.0f - sd / (Ms + EPSF)) + 0.01f;
        float tsc = (1.0f - fabsf(pth - tgth[g]) / (Mt + EPSF)) + 0.01f;
        float r = (dsc * xsc) * tsc;
        float cost = -(r * r) * 3.0f + cls;
        if (cost < bc) { bc = cost; bg = g; }   // strict < == argmin first-occurrence
      }
      matched = bg;
    }
    out[b * PN + p] = assigned;
    out[BN * PN + b * PN + p] = matched;
  }
}

extern "C" void kernel_launch(void* const* d_in, const int* in_sizes, int n_in,
                              void* d_out, int out_size, void* d_ws, size_t ws_size,
                              hipStream_t stream) {
  const float* preds   = (const float*)d_in[0];
  const float* targets = (const float*)d_in[1];
  const void*  masks   = (const void*)d_in[2];
  const int*   imw     = (const int*)d_in[3];
  const int*   imh     = (const int*)d_in[4];
  float* ws = (float*)d_ws;
  int*   out = (int*)d_out;

  hipLaunchKernelGGL(clr_k1, dim3(CHN, BN), dim3(512), 0, stream,
                     preds, targets, masks, imw, imh, ws);
  hipLaunchKernelGGL(clr_k2, dim3(GN, BN), dim3(256), 0, stream,
                     targets, imw, imh, ws);
  hipLaunchKernelGGL(clr_k3, dim3(BN), dim3(256), 0, stream,
                     targets, masks, imw, imh, ws, out);
}